// Round 5
// baseline (652.612 us; speedup 1.0000x reference)
//
#include <hip/hip_runtime.h>

typedef short short8 __attribute__((ext_vector_type(8)));
typedef _Float16 half8 __attribute__((ext_vector_type(8)));
typedef float f32x4 __attribute__((ext_vector_type(4)));
typedef unsigned short u16;

#define MFMA16H(a,b,c) __builtin_amdgcn_mfma_f32_16x16x32_f16((a),(b),(c),0,0,0)

__device__ __forceinline__ u16 f2h(float f){
  _Float16 h = (_Float16)f;
  return __builtin_bit_cast(u16, h);
}
__device__ __forceinline__ float h2f(u16 u){
  _Float16 h = __builtin_bit_cast(_Float16, u);
  return (float)h;
}
__device__ __forceinline__ float sigmoidf_(float x){
  return 1.0f / (1.0f + __expf(-x));
}
__device__ __forceinline__ half8 ldh8(const u16* p){ return *(const half8*)p; }

#define PLANE 262144    // 512*512 elements per d-plane

// ---------------- weight prep: f32 -> fp16 ----------------
// wbuf (u16): [0,32768) p_in ; [32768,65536) g_in ; [65536,81920) p_out ;
//             [81920,98304) g_out
__global__ __launch_bounds__(256) void prep_w(
    const float* __restrict__ p_in, const float* __restrict__ g_in,
    const float* __restrict__ p_out, const float* __restrict__ g_out,
    u16* __restrict__ wbuf)
{
  int idx = blockIdx.x * 256 + threadIdx.x;   // 0..98303
  float v;
  if (idx < 32768)       v = p_in[idx];
  else if (idx < 65536)  v = g_in[idx - 32768];
  else if (idx < 81920)  v = p_out[idx - 65536];
  else                   v = g_out[idx - 81920];
  wbuf[idx] = f2h(v);
}

// ---------------- stage 1: LN + dual projection + gate ----------------
// 64 pixels/block (one row i, 64 consecutive k), 256 threads.
// Weights read L2->registers (no LDS, no weight barriers); hT double-buffered
// so each h-slice needs exactly one barrier. 5 barriers total.
__global__ __launch_bounds__(256) void stage1(
    const float* __restrict__ x,
    const float* __restrict__ niw, const float* __restrict__ nib,
    const u16* __restrict__ wbuf,
    u16* __restrict__ a_h, u16* __restrict__ a_l,
    u16* __restrict__ b_h, u16* __restrict__ b_l,
    u16* __restrict__ gate)
{
  __shared__ __align__(16) u16 xnT[64*136];      // [px][c]
  __shared__ __align__(16) u16 hTh[2][64*72];    // [buf][ch][px]
  __shared__ __align__(16) u16 hTl[2][64*72];

  int t = threadIdx.x;
  int p0 = blockIdx.x * 64;
  int i_row = p0 >> 9, k0 = p0 & 511;

  // ---- LayerNorm: 4 threads per pixel ----
  {
    int px = t >> 2, part = t & 3;
    const float* xr = x + (size_t)(p0 + px) * 128 + part * 32;
    float v[32];
    float s = 0.f, ss = 0.f;
#pragma unroll
    for (int q = 0; q < 8; ++q) {
      float4 f = *(const float4*)(xr + q * 4);
      v[q*4+0] = f.x; v[q*4+1] = f.y; v[q*4+2] = f.z; v[q*4+3] = f.w;
      s  += f.x + f.y + f.z + f.w;
      ss += f.x*f.x + f.y*f.y + f.z*f.z + f.w*f.w;
    }
    s  += __shfl_xor(s, 1);  s  += __shfl_xor(s, 2);
    ss += __shfl_xor(ss, 1); ss += __shfl_xor(ss, 2);
    float m  = s * (1.f/128.f);
    float var = ss * (1.f/128.f) - m*m;
    float rs = rsqrtf(var + 1e-5f);
#pragma unroll
    for (int q = 0; q < 4; ++q) {
      short8 o;
#pragma unroll
      for (int j = 0; j < 8; ++j) {
        int c = part*32 + q*8 + j;
        float xv = (v[q*8+j] - m) * rs * niw[c] + nib[c];
        o[j] = (short)f2h(xv);
      }
      *(short8*)&xnT[px*136 + part*32 + q*8] = o;
    }
  }
  __syncthreads();

  int wave = t >> 6, lane = t & 63;
  int fr = lane & 15, hi = lane >> 4;
  int m0 = wave * 16;

  half8 afr[4];
#pragma unroll
  for (int kk = 0; kk < 4; ++kk)
    afr[kk] = ldh8(&xnT[(m0 + fr)*136 + kk*32 + hi*8]);

  for (int ns = 0; ns < 6; ++ns) {
    const u16* wP;
    const u16* wG = nullptr;
    if (ns < 4) {
      int n0 = ns * 64;
      wP = wbuf + n0*128;
      wG = wbuf + 32768 + n0*128;
    } else {
      int n0 = (ns - 4) * 64;
      wP = wbuf + 81920 + n0*128;
    }

    f32x4 accP[4] = {}, accG[4] = {};
#pragma unroll
    for (int kk = 0; kk < 4; ++kk) {
#pragma unroll
      for (int nf = 0; nf < 4; ++nf) {
        half8 bp = ldh8(&wP[(nf*16 + fr)*128 + kk*32 + hi*8]);
        accP[nf] = MFMA16H(afr[kk], bp, accP[nf]);
        if (ns < 4) {
          half8 bg = ldh8(&wG[(nf*16 + fr)*128 + kk*32 + hi*8]);
          accG[nf] = MFMA16H(afr[kk], bg, accG[nf]);
        }
      }
    }

    if (ns < 4) {
      int bufi = ns & 1;
#pragma unroll
      for (int nf = 0; nf < 4; ++nf) {
#pragma unroll
        for (int r = 0; r < 4; ++r) {
          float h = accP[nf][r] * sigmoidf_(accG[nf][r]);
          int nl = nf*16 + fr;
          int pl = m0 + hi*4 + r;
          u16 hh = f2h(h);
          hTh[bufi][nl*72 + pl] = hh;
          hTl[bufi][nl*72 + pl] = f2h(h - h2f(hh));
        }
      }
      __syncthreads();
      int n0 = ns * 64;
      u16* dh = (ns < 2) ? a_h : b_h;
      u16* dl = (ns < 2) ? a_l : b_l;
      int dbase = (ns < 2) ? n0 : n0 - 128;
      int nl = t >> 2, po = (t & 3) * 16;
      size_t g = (size_t)(dbase + nl) * PLANE + (size_t)i_row * 512 + k0 + po;
      *(short8*)&dh[g]     = *(const short8*)&hTh[bufi][nl*72 + po];
      *(short8*)&dh[g + 8] = *(const short8*)&hTh[bufi][nl*72 + po + 8];
      *(short8*)&dl[g]     = *(const short8*)&hTl[bufi][nl*72 + po];
      *(short8*)&dl[g + 8] = *(const short8*)&hTl[bufi][nl*72 + po + 8];
    } else {
      int n0 = (ns - 4) * 64;
#pragma unroll
      for (int nf = 0; nf < 4; ++nf) {
#pragma unroll
        for (int r = 0; r < 4; ++r) {
          float gv = sigmoidf_(accP[nf][r]);
          int cc = n0 + nf*16 + fr;
          int pl = m0 + hi*4 + r;
          gate[(size_t)(p0 + pl)*128 + cc] = f2h(gv);
        }
      }
    }
  }
}

// ---------------- stage 2: 128 batched 512x512x512 NT GEMMs (split a,b) ----
// 128x128 tile, BK=64, 4 waves 2x2, register prefetch, t stored single fp16
__global__ __launch_bounds__(256, 2) void stage2(
    const u16* __restrict__ a_h, const u16* __restrict__ a_l,
    const u16* __restrict__ b_h, const u16* __restrict__ b_l,
    u16* __restrict__ t_h)
{
  int bid = blockIdx.x;
  int d  = bid >> 4;
  int it = (bid >> 2) & 3;
  int jt = bid & 3;
  size_t abase = (size_t)d * PLANE + (size_t)it * 128 * 512;
  size_t bbase = (size_t)d * PLANE + (size_t)jt * 128 * 512;

  __shared__ __align__(16) u16 Ash[128*72], Bsh[128*72];
  __shared__ __align__(16) u16 Asl[128*72], Bsl[128*72];

  int t = threadIdx.x, wave = t >> 6, lane = t & 63;
  int fr = lane & 15, hi = lane >> 4;
  int m0 = (wave & 1) * 64, n0 = (wave >> 1) * 64;
  int srow = t >> 1, sko = (t & 1) * 32;

  f32x4 acc[4][4] = {};
  short8 rah[4], ral[4], rbh[4], rbl[4];

#pragma unroll
  for (int q = 0; q < 4; ++q) {
    size_t go = (size_t)srow*512 + sko + q*8;
    rah[q] = *(const short8*)&a_h[abase + go];
    ral[q] = *(const short8*)&a_l[abase + go];
    rbh[q] = *(const short8*)&b_h[bbase + go];
    rbl[q] = *(const short8*)&b_l[bbase + go];
  }

  for (int step = 0; step < 8; ++step) {
    __syncthreads();          // prev compute done, LDS free
#pragma unroll
    for (int q = 0; q < 4; ++q) {
      *(short8*)&Ash[srow*72 + sko + q*8] = rah[q];
      *(short8*)&Asl[srow*72 + sko + q*8] = ral[q];
      *(short8*)&Bsh[srow*72 + sko + q*8] = rbh[q];
      *(short8*)&Bsl[srow*72 + sko + q*8] = rbl[q];
    }
    if (step < 7) {
      int kb = (step + 1) * 64;
#pragma unroll
      for (int q = 0; q < 4; ++q) {
        size_t go = (size_t)srow*512 + kb + sko + q*8;
        rah[q] = *(const short8*)&a_h[abase + go];
        ral[q] = *(const short8*)&a_l[abase + go];
        rbh[q] = *(const short8*)&b_h[bbase + go];
        rbl[q] = *(const short8*)&b_l[bbase + go];
      }
    }
    __syncthreads();
#pragma unroll
    for (int kk = 0; kk < 2; ++kk) {
      half8 afh[4], bfh[4], afl[4], bfl[4];
#pragma unroll
      for (int mf = 0; mf < 4; ++mf) {
        afh[mf] = ldh8(&Ash[(m0 + mf*16 + fr)*72 + kk*32 + hi*8]);
        afl[mf] = ldh8(&Asl[(m0 + mf*16 + fr)*72 + kk*32 + hi*8]);
      }
#pragma unroll
      for (int nf = 0; nf < 4; ++nf) {
        bfh[nf] = ldh8(&Bsh[(n0 + nf*16 + fr)*72 + kk*32 + hi*8]);
        bfl[nf] = ldh8(&Bsl[(n0 + nf*16 + fr)*72 + kk*32 + hi*8]);
      }
#pragma unroll
      for (int mf = 0; mf < 4; ++mf)
#pragma unroll
        for (int nf = 0; nf < 4; ++nf) {
          acc[mf][nf] = MFMA16H(afh[mf], bfh[nf], acc[mf][nf]);
          acc[mf][nf] = MFMA16H(afh[mf], bfl[nf], acc[mf][nf]);
          acc[mf][nf] = MFMA16H(afl[mf], bfh[nf], acc[mf][nf]);
        }
    }
  }

  u16* T = t_h + (size_t)d * PLANE;
  int ibase = it*128 + m0, jbase = jt*128 + n0;
#pragma unroll
  for (int mf = 0; mf < 4; ++mf)
#pragma unroll
    for (int r = 0; r < 4; ++r) {
      int i = ibase + mf*16 + hi*4 + r;
#pragma unroll
      for (int nf = 0; nf < 4; ++nf) {
        int j = jbase + nf*16 + fr;
        T[(size_t)i*512 + j] = f2h(acc[mf][nf][r]);
      }
    }
}

// ---------------- stage 3: LN over d + out projection * gate ----------------
// 64 pixels/block; p_out weights direct from L2 (no LDS); 2 barriers
__global__ __launch_bounds__(256) void stage3(
    const u16* __restrict__ t_h, const u16* __restrict__ gate,
    const float* __restrict__ now_, const float* __restrict__ nob_,
    const u16* __restrict__ wbuf, float* __restrict__ out)
{
  __shared__ __align__(16) u16 tTh[128*72];   // [d][j]
  __shared__ __align__(16) u16 onT[64*136];   // [px][h]

  int t = threadIdx.x;
  int p0 = blockIdx.x * 64;
  int i_row = p0 >> 9, j0 = p0 & 511;

  {
    int srow = t >> 1, sko = (t & 1) * 32;
#pragma unroll
    for (int q = 0; q < 4; ++q)
      *(short8*)&tTh[srow*72 + sko + q*8] =
        *(const short8*)&t_h[(size_t)srow * PLANE + (size_t)i_row*512 + j0 + sko + q*8];
  }
  __syncthreads();

  // LN over d: 4 threads per pixel
  {
    int px = t >> 2, part = t & 3;
    float tv[32]; float s = 0.f, ss = 0.f;
#pragma unroll
    for (int q = 0; q < 32; ++q) {
      int d = part*32 + q;
      float f = h2f(tTh[d*72 + px]);
      tv[q] = f; s += f; ss += f*f;
    }
    s  += __shfl_xor(s, 1);  s  += __shfl_xor(s, 2);
    ss += __shfl_xor(ss, 1); ss += __shfl_xor(ss, 2);
    float m = s * (1.f/128.f);
    float var = ss * (1.f/128.f) - m*m;
    float rs = rsqrtf(var + 1e-5f);
#pragma unroll
    for (int q = 0; q < 4; ++q) {
      short8 o;
#pragma unroll
      for (int j = 0; j < 8; ++j) {
        int d = part*32 + q*8 + j;
        o[j] = (short)f2h((tv[q*8+j] - m) * rs * now_[d] + nob_[d]);
      }
      *(short8*)&onT[px*136 + part*32 + q*8] = o;
    }
  }
  __syncthreads();

  int wave = t >> 6, lane = t & 63;
  int fr = lane & 15, hi = lane >> 4;
  int m0 = wave * 16;
  half8 af[4];
#pragma unroll
  for (int kk = 0; kk < 4; ++kk)
    af[kk] = ldh8(&onT[(m0 + fr)*136 + kk*32 + hi*8]);
  const u16* wpo = wbuf + 65536;
  f32x4 acc[8] = {};
#pragma unroll
  for (int kk = 0; kk < 4; ++kk)
#pragma unroll
    for (int nf = 0; nf < 8; ++nf)
      acc[nf] = MFMA16H(af[kk], ldh8(&wpo[(nf*16 + fr)*128 + kk*32 + hi*8]), acc[nf]);

#pragma unroll
  for (int nf = 0; nf < 8; ++nf)
#pragma unroll
    for (int r = 0; r < 4; ++r) {
      int pl = m0 + hi*4 + r;
      int cc = nf*16 + fr;
      size_t gi = (size_t)(p0 + pl) * 128 + cc;
      out[gi] = acc[nf][r] * h2f(gate[gi]);
    }
}

extern "C" void kernel_launch(void* const* d_in, const int* in_sizes, int n_in,
                              void* d_out, int out_size, void* d_ws, size_t ws_size,
                              hipStream_t stream) {
  const float* x   = (const float*)d_in[0];
  const float* niw = (const float*)d_in[1];
  const float* nib = (const float*)d_in[2];
  const float* piw = (const float*)d_in[3];
  const float* giw = (const float*)d_in[4];
  const float* now_ = (const float*)d_in[5];
  const float* nob_ = (const float*)d_in[6];
  const float* pow_ = (const float*)d_in[7];
  const float* gow  = (const float*)d_in[8];
  float* out = (float*)d_out;

  char* ws = (char*)d_ws;
  const size_t MB = 1048576;
  u16* a_h  = (u16*)(ws);
  u16* a_l  = (u16*)(ws + 64*MB);
  u16* b_h  = (u16*)(ws + 128*MB);
  u16* b_l  = (u16*)(ws + 192*MB);
  u16* gate = (u16*)(ws + 256*MB);
  u16* t_h  = (u16*)(ws + 320*MB);
  u16* wbuf = (u16*)(ws + 384*MB);

  prep_w<<<384, 256, 0, stream>>>(piw, giw, pow_, gow, wbuf);
  stage1<<<4096, 256, 0, stream>>>(x, niw, nib, wbuf, a_h, a_l, b_h, b_l, gate);
  stage2<<<2048, 256, 0, stream>>>(a_h, a_l, b_h, b_l, t_h);
  stage3<<<4096, 256, 0, stream>>>(t_h, gate, now_, nob_, wbuf, out);
}

// Round 7
// 464.626 us; speedup vs baseline: 1.4046x; 1.4046x over previous
//
#include <hip/hip_runtime.h>

typedef short short8 __attribute__((ext_vector_type(8)));
typedef _Float16 half8 __attribute__((ext_vector_type(8)));
typedef float f32x4 __attribute__((ext_vector_type(4)));
typedef unsigned short u16;

#define MFMA16H(a,b,c) __builtin_amdgcn_mfma_f32_16x16x32_f16((a),(b),(c),0,0,0)

__device__ __forceinline__ u16 f2h(float f){
  _Float16 h = (_Float16)f;
  return __builtin_bit_cast(u16, h);
}
__device__ __forceinline__ float h2f(u16 u){
  _Float16 h = __builtin_bit_cast(_Float16, u);
  return (float)h;
}
__device__ __forceinline__ float sigmoidf_(float x){
  return 1.0f / (1.0f + __expf(-x));
}
__device__ __forceinline__ half8 ldh8(const u16* p){ return *(const half8*)p; }

#define PLANE 262144    // 512*512 elements per d-plane

// ---------------- weight prep: f32 -> fp16 ----------------
// wbuf (u16): [0,32768) p_in ; [32768,65536) g_in ; [65536,81920) p_out ;
//             [81920,98304) g_out
__global__ __launch_bounds__(256) void prep_w(
    const float* __restrict__ p_in, const float* __restrict__ g_in,
    const float* __restrict__ p_out, const float* __restrict__ g_out,
    u16* __restrict__ wbuf)
{
  int idx = blockIdx.x * 256 + threadIdx.x;   // 0..98303
  float v;
  if (idx < 32768)       v = p_in[idx];
  else if (idx < 65536)  v = g_in[idx - 32768];
  else if (idx < 81920)  v = p_out[idx - 65536];
  else                   v = g_out[idx - 81920];
  wbuf[idx] = f2h(v);
}

// ---------------- stage 1: LN + dual projection + gate ----------------
// EXACT copy of the R4-passing stage1 (S=true specialization).
// Separate LDS buffers — NO unioning (R6 union corrupted results).
__global__ __launch_bounds__(256) void stage1(
    const float* __restrict__ x,
    const float* __restrict__ niw, const float* __restrict__ nib,
    const u16* __restrict__ wbuf,
    u16* __restrict__ a_h, u16* __restrict__ a_l,
    u16* __restrict__ b_h, u16* __restrict__ b_l,
    u16* __restrict__ gate)
{
  __shared__ __align__(16) u16 xnT[64*136];
  __shared__ __align__(16) u16 wp [64*136];
  __shared__ __align__(16) u16 wg [64*136];
  __shared__ __align__(16) u16 hTh[64*72];
  __shared__ __align__(16) u16 hTl[64*72];

  int t = threadIdx.x;
  int p0 = blockIdx.x * 64;
  int i_row = p0 >> 9, k0 = p0 & 511;

  {
    int px = t >> 2, part = t & 3;
    const float* xr = x + (size_t)(p0 + px) * 128 + part * 32;
    float v[32];
    float s = 0.f, ss = 0.f;
#pragma unroll
    for (int q = 0; q < 8; ++q) {
      float4 f = *(const float4*)(xr + q * 4);
      v[q*4+0] = f.x; v[q*4+1] = f.y; v[q*4+2] = f.z; v[q*4+3] = f.w;
      s  += f.x + f.y + f.z + f.w;
      ss += f.x*f.x + f.y*f.y + f.z*f.z + f.w*f.w;
    }
    s  += __shfl_xor(s, 1);  s  += __shfl_xor(s, 2);
    ss += __shfl_xor(ss, 1); ss += __shfl_xor(ss, 2);
    float m  = s * (1.f/128.f);
    float var = ss * (1.f/128.f) - m*m;
    float rs = rsqrtf(var + 1e-5f);
#pragma unroll
    for (int q = 0; q < 4; ++q) {
      short8 o;
#pragma unroll
      for (int j = 0; j < 8; ++j) {
        int c = part*32 + q*8 + j;
        float xv = (v[q*8+j] - m) * rs * niw[c] + nib[c];
        o[j] = (short)f2h(xv);
      }
      *(short8*)&xnT[px*136 + part*32 + q*8] = o;
    }
  }
  __syncthreads();

  int wave = t >> 6, lane = t & 63;
  int fr = lane & 15, hi = lane >> 4;
  int m0 = wave * 16;

  half8 afr[4];
#pragma unroll
  for (int kk = 0; kk < 4; ++kk)
    afr[kk] = ldh8(&xnT[(m0 + fr)*136 + kk*32 + hi*8]);

  for (int ns = 0; ns < 6; ++ns) {
    __syncthreads();
    if (ns < 4) {
      int n0 = ns * 64;
#pragma unroll
      for (int q = 0; q < 4; ++q) {
        int c = t + q*256;
        int row = c >> 4, ko = (c & 15) * 8;
        *(short8*)&wp[row*136 + ko] = *(const short8*)&wbuf[n0*128 + row*128 + ko];
        *(short8*)&wg[row*136 + ko] = *(const short8*)&wbuf[32768 + n0*128 + row*128 + ko];
      }
    } else {
      int n0 = (ns - 4) * 64;
#pragma unroll
      for (int q = 0; q < 4; ++q) {
        int c = t + q*256;
        int row = c >> 4, ko = (c & 15) * 8;
        *(short8*)&wp[row*136 + ko] = *(const short8*)&wbuf[81920 + n0*128 + row*128 + ko];
      }
    }
    __syncthreads();

    f32x4 accP[4] = {}, accG[4] = {};
#pragma unroll
    for (int kk = 0; kk < 4; ++kk) {
#pragma unroll
      for (int nf = 0; nf < 4; ++nf) {
        half8 bp = ldh8(&wp[(nf*16 + fr)*136 + kk*32 + hi*8]);
        accP[nf] = MFMA16H(afr[kk], bp, accP[nf]);
        if (ns < 4) {
          half8 bg = ldh8(&wg[(nf*16 + fr)*136 + kk*32 + hi*8]);
          accG[nf] = MFMA16H(afr[kk], bg, accG[nf]);
        }
      }
    }

    if (ns < 4) {
#pragma unroll
      for (int nf = 0; nf < 4; ++nf) {
#pragma unroll
        for (int r = 0; r < 4; ++r) {
          float h = accP[nf][r] * sigmoidf_(accG[nf][r]);
          int nl = nf*16 + fr;
          int pl = m0 + hi*4 + r;
          u16 hh = f2h(h);
          hTh[nl*72 + pl] = hh;
          hTl[nl*72 + pl] = f2h(h - h2f(hh));
        }
      }
      __syncthreads();
      int n0 = ns * 64;
      u16* dh = (ns < 2) ? a_h : b_h;
      u16* dl = (ns < 2) ? a_l : b_l;
      int dbase = (ns < 2) ? n0 : n0 - 128;
      int nl = t >> 2, po = (t & 3) * 16;
      size_t g = (size_t)(dbase + nl) * PLANE + (size_t)i_row * 512 + k0 + po;
      *(short8*)&dh[g]     = *(const short8*)&hTh[nl*72 + po];
      *(short8*)&dh[g + 8] = *(const short8*)&hTh[nl*72 + po + 8];
      *(short8*)&dl[g]     = *(const short8*)&hTl[nl*72 + po];
      *(short8*)&dl[g + 8] = *(const short8*)&hTl[nl*72 + po + 8];
    } else {
      int n0 = (ns - 4) * 64;
#pragma unroll
      for (int nf = 0; nf < 4; ++nf) {
#pragma unroll
        for (int r = 0; r < 4; ++r) {
          float gv = sigmoidf_(accP[nf][r]);
          int cc = n0 + nf*16 + fr;
          int pl = m0 + hi*4 + r;
          gate[(size_t)(p0 + pl)*128 + cc] = f2h(gv);
        }
      }
    }
  }
}

// ---------------- stage 2: 128 batched 512x512x512 NT GEMMs (split a,b) ----
// 128x128 tile, BK=64, 4 waves 2x2, register prefetch, split-t output.
// XCD swizzle: 16 (it,jt) blocks of one d-plane land on one XCD.
__global__ __launch_bounds__(256, 2) void stage2(
    const u16* __restrict__ a_h, const u16* __restrict__ a_l,
    const u16* __restrict__ b_h, const u16* __restrict__ b_l,
    u16* __restrict__ t_h, u16* __restrict__ t_l)
{
  int bid = blockIdx.x;
  int xcd = bid & 7;
  int idx = bid >> 3;              // 0..255
  int d   = xcd + (idx >> 4) * 8;  // 16 d's per XCD
  int sub = idx & 15;
  int it = sub >> 2;
  int jt = sub & 3;
  size_t abase = (size_t)d * PLANE + (size_t)it * 128 * 512;
  size_t bbase = (size_t)d * PLANE + (size_t)jt * 128 * 512;

  __shared__ __align__(16) u16 Ash[128*72], Bsh[128*72];
  __shared__ __align__(16) u16 Asl[128*72], Bsl[128*72];

  int t = threadIdx.x, wave = t >> 6, lane = t & 63;
  int fr = lane & 15, hi = lane >> 4;
  int m0 = (wave & 1) * 64, n0 = (wave >> 1) * 64;
  int srow = t >> 1, sko = (t & 1) * 32;

  f32x4 acc[4][4] = {};
  short8 rah[4], ral[4], rbh[4], rbl[4];

#pragma unroll
  for (int q = 0; q < 4; ++q) {
    size_t go = (size_t)srow*512 + sko + q*8;
    rah[q] = *(const short8*)&a_h[abase + go];
    ral[q] = *(const short8*)&a_l[abase + go];
    rbh[q] = *(const short8*)&b_h[bbase + go];
    rbl[q] = *(const short8*)&b_l[bbase + go];
  }

  for (int step = 0; step < 8; ++step) {
    __syncthreads();
#pragma unroll
    for (int q = 0; q < 4; ++q) {
      *(short8*)&Ash[srow*72 + sko + q*8] = rah[q];
      *(short8*)&Asl[srow*72 + sko + q*8] = ral[q];
      *(short8*)&Bsh[srow*72 + sko + q*8] = rbh[q];
      *(short8*)&Bsl[srow*72 + sko + q*8] = rbl[q];
    }
    if (step < 7) {
      int kb = (step + 1) * 64;
#pragma unroll
      for (int q = 0; q < 4; ++q) {
        size_t go = (size_t)srow*512 + kb + sko + q*8;
        rah[q] = *(const short8*)&a_h[abase + go];
        ral[q] = *(const short8*)&a_l[abase + go];
        rbh[q] = *(const short8*)&b_h[bbase + go];
        rbl[q] = *(const short8*)&b_l[bbase + go];
      }
    }
    __syncthreads();
#pragma unroll
    for (int kk = 0; kk < 2; ++kk) {
      half8 afh[4], bfh[4], afl[4], bfl[4];
#pragma unroll
      for (int mf = 0; mf < 4; ++mf) {
        afh[mf] = ldh8(&Ash[(m0 + mf*16 + fr)*72 + kk*32 + hi*8]);
        afl[mf] = ldh8(&Asl[(m0 + mf*16 + fr)*72 + kk*32 + hi*8]);
      }
#pragma unroll
      for (int nf = 0; nf < 4; ++nf) {
        bfh[nf] = ldh8(&Bsh[(n0 + nf*16 + fr)*72 + kk*32 + hi*8]);
        bfl[nf] = ldh8(&Bsl[(n0 + nf*16 + fr)*72 + kk*32 + hi*8]);
      }
#pragma unroll
      for (int mf = 0; mf < 4; ++mf)
#pragma unroll
        for (int nf = 0; nf < 4; ++nf) {
          acc[mf][nf] = MFMA16H(afh[mf], bfh[nf], acc[mf][nf]);
          acc[mf][nf] = MFMA16H(afh[mf], bfl[nf], acc[mf][nf]);
          acc[mf][nf] = MFMA16H(afl[mf], bfh[nf], acc[mf][nf]);
        }
    }
  }

  u16* Th = t_h + (size_t)d * PLANE;
  u16* Tl = t_l + (size_t)d * PLANE;
  int ibase = it*128 + m0, jbase = jt*128 + n0;
#pragma unroll
  for (int mf = 0; mf < 4; ++mf)
#pragma unroll
    for (int r = 0; r < 4; ++r) {
      int i = ibase + mf*16 + hi*4 + r;
#pragma unroll
      for (int nf = 0; nf < 4; ++nf) {
        int j = jbase + nf*16 + fr;
        float v = acc[mf][nf][r];
        u16 vh = f2h(v);
        Th[(size_t)i*512 + j] = vh;
        Tl[(size_t)i*512 + j] = f2h(v - h2f(vh));
      }
    }
}

// ---------------- stage 3: LN over d + out projection * gate ----------------
// 64 pixels/block; p_out weights direct from L2 (identical values to LDS path)
__global__ __launch_bounds__(256) void stage3(
    const u16* __restrict__ t_h, const u16* __restrict__ t_l,
    const u16* __restrict__ gate,
    const float* __restrict__ now_, const float* __restrict__ nob_,
    const u16* __restrict__ wbuf, float* __restrict__ out)
{
  __shared__ __align__(16) u16 tTh[128*72];   // [d][j]
  __shared__ __align__(16) u16 tTl[128*72];
  __shared__ __align__(16) u16 onT[64*136];   // [px][h]

  int t = threadIdx.x;
  int p0 = blockIdx.x * 64;
  int i_row = p0 >> 9, j0 = p0 & 511;

  {
    int srow = t >> 1, sko = (t & 1) * 32;
#pragma unroll
    for (int q = 0; q < 4; ++q) {
      size_t go = (size_t)srow * PLANE + (size_t)i_row*512 + j0 + sko + q*8;
      *(short8*)&tTh[srow*72 + sko + q*8] = *(const short8*)&t_h[go];
      *(short8*)&tTl[srow*72 + sko + q*8] = *(const short8*)&t_l[go];
    }
  }
  __syncthreads();

  {
    int px = t >> 2, part = t & 3;
    float tv[32]; float s = 0.f, ss = 0.f;
#pragma unroll
    for (int q = 0; q < 32; ++q) {
      int d = part*32 + q;
      float f = h2f(tTh[d*72 + px]) + h2f(tTl[d*72 + px]);
      tv[q] = f; s += f; ss += f*f;
    }
    s  += __shfl_xor(s, 1);  s  += __shfl_xor(s, 2);
    ss += __shfl_xor(ss, 1); ss += __shfl_xor(ss, 2);
    float m = s * (1.f/128.f);
    float var = ss * (1.f/128.f) - m*m;
    float rs = rsqrtf(var + 1e-5f);
#pragma unroll
    for (int q = 0; q < 4; ++q) {
      short8 o;
#pragma unroll
      for (int j = 0; j < 8; ++j) {
        int d = part*32 + q*8 + j;
        o[j] = (short)f2h((tv[q*8+j] - m) * rs * now_[d] + nob_[d]);
      }
      *(short8*)&onT[px*136 + part*32 + q*8] = o;
    }
  }
  __syncthreads();

  int wave = t >> 6, lane = t & 63;
  int fr = lane & 15, hi = lane >> 4;
  int m0 = wave * 16;
  half8 af[4];
#pragma unroll
  for (int kk = 0; kk < 4; ++kk)
    af[kk] = ldh8(&onT[(m0 + fr)*136 + kk*32 + hi*8]);
  const u16* wpo = wbuf + 65536;
  f32x4 acc[8] = {};
#pragma unroll
  for (int kk = 0; kk < 4; ++kk)
#pragma unroll
    for (int nf = 0; nf < 8; ++nf)
      acc[nf] = MFMA16H(af[kk], ldh8(&wpo[(nf*16 + fr)*128 + kk*32 + hi*8]), acc[nf]);

#pragma unroll
  for (int nf = 0; nf < 8; ++nf)
#pragma unroll
    for (int r = 0; r < 4; ++r) {
      int pl = m0 + hi*4 + r;
      int cc = nf*16 + fr;
      size_t gi = (size_t)(p0 + pl) * 128 + cc;
      out[gi] = acc[nf][r] * h2f(gate[gi]);
    }
}

extern "C" void kernel_launch(void* const* d_in, const int* in_sizes, int n_in,
                              void* d_out, int out_size, void* d_ws, size_t ws_size,
                              hipStream_t stream) {
  const float* x   = (const float*)d_in[0];
  const float* niw = (const float*)d_in[1];
  const float* nib = (const float*)d_in[2];
  const float* piw = (const float*)d_in[3];
  const float* giw = (const float*)d_in[4];
  const float* now_ = (const float*)d_in[5];
  const float* nob_ = (const float*)d_in[6];
  const float* pow_ = (const float*)d_in[7];
  const float* gow  = (const float*)d_in[8];
  float* out = (float*)d_out;

  char* ws = (char*)d_ws;
  const size_t MB = 1048576;
  u16* a_h  = (u16*)(ws);
  u16* a_l  = (u16*)(ws + 64*MB);
  u16* b_h  = (u16*)(ws + 128*MB);
  u16* b_l  = (u16*)(ws + 192*MB);
  u16* gate = (u16*)(ws + 256*MB);
  u16* t_h  = (u16*)(ws + 320*MB);
  u16* t_l  = (u16*)(ws + 384*MB);
  u16* wbuf = (u16*)(ws + 448*MB);

  prep_w<<<384, 256, 0, stream>>>(piw, giw, pow_, gow, wbuf);
  stage1<<<4096, 256, 0, stream>>>(x, niw, nib, wbuf, a_h, a_l, b_h, b_l, gate);
  stage2<<<2048, 256, 0, stream>>>(a_h, a_l, b_h, b_l, t_h, t_l);
  stage3<<<4096, 256, 0, stream>>>(t_h, t_l, gate, now_, nob_, wbuf, out);
}